// Round 10
// baseline (225.827 us; speedup 1.0000x reference)
//
#include <hip/hip_runtime.h>

// Conv2dFusion v6: wave-specialized fused pipeline, forcing 2 blocks/CU.
// Per image: 128x128 rank-1 map -> conv0(1->32)+GELU+pool (VALU, H-table, GELU-after-max)
//   -> conv1(32->64)+GELU+pool (MFMA, waves 0-3) -> P1 6-row LDS ring
//   -> conv2(64->64)+GELU+pool (MFMA, waves 4-7, interleaved) -> out.
// v6 occupancy unblock (round-9 evidence: VGPR=112 arch + 2x16 AGPR acc arrays
// = 144 unified > 128 -> 3 waves/SIMD -> 1 block/CU):
//   (a) amdgpu_waves_per_eu(4): force allocator to <=128 unified regs,
//   (b) ONE shared f32x4 acc[4] across conv1/conv2/tail (structural AGPR share),
//   (c) LDS 65,664 -> 65,152 B: tk staging aliased onto P1 ring (tk dead after
//       H-build; P1 first written at i1=0 epilogue).
// v4 lesson kept: __launch_bounds__(512,2) second arg is CUDA min-blocks.

typedef short short8 __attribute__((ext_vector_type(8)));
typedef float f32x4 __attribute__((ext_vector_type(4)));

#define OFF_TY   0                    // f32[128] = 512 B
#define OFF_HLO  512                  // u32[32*126] = 16128 B
#define OFF_HHI  16640                // u16[32*126] = 8064 B
#define OFF_P0   24704                // 4 slots * 264 units * 16B = 16896 B
#define OFF_P1   41600                // ring 6 rows*240 units + 32 pad = 1472 units
#define OFF_TK   OFF_P1              // f32[128], dead before first P1 write
#define LDS_TOTAL (41600 + 1472*16)   // 65,152 B  (2 blocks = 130,304 <= 160 KiB)

__device__ __forceinline__ unsigned short f2bf(float f) {
    unsigned int u = __float_as_uint(f);
    u += 0x7fffu + ((u >> 16) & 1u);   // RNE
    return (unsigned short)(u >> 16);
}

// erf-GELU via A&S 7.1.25 (|err| <= 2.5e-5), branch-free.
__device__ __forceinline__ float gelu_f(float x) {
    float ax = __builtin_fabsf(x);
    float E  = __builtin_amdgcn_exp2f(x * x * -0.72134752f);
    float k  = __builtin_amdgcn_rcpf(__builtin_fmaf(0.33267686f, ax, 1.0f));
    float s  = __builtin_fmaf(0.7478556f, k, -0.0958798f);
    s = __builtin_fmaf(s, k, 0.3480242f);
    s = s * k;
    float erfabs = __builtin_fmaf(-s, E, 1.0f);
    return __builtin_fmaf(0.5f * ax, erfabs, 0.5f * x);
}

// pool0 producer: pooled rows R0, R0+1 into P0 ring (GELU applied after max).
__device__ __forceinline__ void produce(char* smem, const float* tys,
                                        float b0r, int c, int tid, int R0) {
    float t0 = tys[2*R0+0], t1 = tys[2*R0+1], t2 = tys[2*R0+2],
          t3 = tys[2*R0+3], t4 = tys[2*R0+4], t5 = tys[2*R0+5];
    int rest = tid >> 5;
    #pragma unroll
    for (int k = 0; k < 8; ++k, rest += 16) {
        if (rest < 126) {
            int roff = (rest >= 63) ? 1 : 0;
            int q = rest - (roff ? 63 : 0);
            float s0 = roff ? t2 : t0;
            float s1 = roff ? t3 : t1;
            float s2 = roff ? t4 : t2;
            float s3 = roff ? t5 : t3;
            uint2 lo = *(const uint2*)(smem + OFF_HLO + (c*126 + 2*q)*4);
            unsigned int hi = *(const unsigned int*)(smem + OFF_HHI + (c*126 + 2*q)*2);
            float h00 = __uint_as_float(lo.x << 16);
            float h10 = __uint_as_float(lo.x & 0xffff0000u);
            float h01 = __uint_as_float(lo.y << 16);
            float h11 = __uint_as_float(lo.y & 0xffff0000u);
            float h20 = __uint_as_float(hi << 16);
            float h21 = __uint_as_float(hi & 0xffff0000u);
            float e00 = __builtin_fmaf(s0,h00, __builtin_fmaf(s1,h10, __builtin_fmaf(s2,h20, b0r)));
            float e10 = __builtin_fmaf(s1,h00, __builtin_fmaf(s2,h10, __builtin_fmaf(s3,h20, b0r)));
            float e01 = __builtin_fmaf(s0,h01, __builtin_fmaf(s1,h11, __builtin_fmaf(s2,h21, b0r)));
            float e11 = __builtin_fmaf(s1,h01, __builtin_fmaf(s2,h11, __builtin_fmaf(s3,h21, b0r)));
            // GELU after max (monotone for x>-0.75; bias bounded & smoothed downstream)
            float m = gelu_f(fmaxf(fmaxf(e00, e01), fmaxf(e10, e11)));
            int slot = (R0 + roff) & 3;
            int unit = slot*264 + (q>>1)*8 + ((4*(q&1) + (c>>3)) ^ ((q>>1)&7));
            *(unsigned short*)(smem + OFF_P0 + unit*16 + (c&7)*2) = f2bf(m);
        }
    }
}

__attribute__((amdgpu_waves_per_eu(4)))
__launch_bounds__(512, 2)
__global__ void conv_pipeline(const float* __restrict__ token,
                              const float* __restrict__ type_,
                              const float* __restrict__ w0, const float* __restrict__ b0,
                              const float* __restrict__ w1, const float* __restrict__ b1,
                              const float* __restrict__ w2, const float* __restrict__ b2,
                              float* __restrict__ out) {
    extern __shared__ char smem[];
    float* tys = (float*)(smem + OFF_TY);
    float* tks = (float*)(smem + OFF_TK);

    const int tid = threadIdx.x;
    const int img = blockIdx.x;
    const int w   = tid >> 6;
    const int l   = tid & 63;
    const int l15 = l & 15;
    const int lc  = l >> 4;
    const int c0w = tid & 31;

    for (int i = tid; i < 128; i += 512) {
        tys[i] = type_[img*128 + i];
        tks[i] = token[img*128 + i];
    }

    const float b0r = b0[c0w];

    __syncthreads();   // ty/tk visible

    // H[c][x][u] = sum_v w0[c,u,v]*tk[x+v]  (w0r lives only in this scope)
    {
        float w0r[9];
        #pragma unroll
        for (int i = 0; i < 9; ++i) w0r[i] = w0[c0w*9 + i];
        int x = tid >> 5;
        #pragma unroll
        for (int k = 0; k < 8; ++k, x += 16) {
            if (x < 126) {
                float t0 = tks[x], t1 = tks[x+1], t2 = tks[x+2];
                float h0 = __builtin_fmaf(w0r[0],t0, __builtin_fmaf(w0r[1],t1, w0r[2]*t2));
                float h1 = __builtin_fmaf(w0r[3],t0, __builtin_fmaf(w0r[4],t1, w0r[5]*t2));
                float h2 = __builtin_fmaf(w0r[6],t0, __builtin_fmaf(w0r[7],t1, w0r[8]*t2));
                unsigned int lov = (unsigned int)f2bf(h0) | ((unsigned int)f2bf(h1) << 16);
                *(unsigned int*)(smem + OFF_HLO + (c0w*126 + x)*4) = lov;
                *(unsigned short*)(smem + OFF_HHI + (c0w*126 + x)*2) = f2bf(h2);
            }
        }
    }

    // Shared fragment storage: waves 0-3 use wf[0..8] (conv1, nt=w),
    // waves 4-7 use wf[0..17] (conv2, nt=w-4, kh*9+uv).
    short8 wf[18];
    float bias;
    const int ch = ((w & 3) * 16) + l15;       // c1 (waves<4) or c2 (waves>=4)
    if (w < 4) {
        bias = b1[ch];
        #pragma unroll
        for (int uv = 0; uv < 9; ++uv) {
            short8 f;
            #pragma unroll
            for (int j = 0; j < 8; ++j)
                f[j] = (short)f2bf(w1[(ch*32 + 8*lc + j)*9 + uv]);
            wf[uv] = f;
        }
    } else {
        bias = b2[ch];
        #pragma unroll
        for (int kh = 0; kh < 2; ++kh)
            #pragma unroll
            for (int uv = 0; uv < 9; ++uv) {
                short8 f;
                #pragma unroll
                for (int j = 0; j < 8; ++j)
                    f[j] = (short)f2bf(w2[(ch*64 + kh*32 + 8*lc + j)*9 + uv]);
                wf[kh*9 + uv] = f;
            }
    }

    __syncthreads();   // H visible (also guards tk death before P1 writes)

    produce(smem, tys, b0r, c0w, tid, 0);
    produce(smem, tys, b0r, c0w, tid, 2);

    const size_t obase = (size_t)img * 12544;

    // ONE accumulator array shared by conv1 halves / conv2 / tail (16 AGPRs).
    f32x4 acc[4];

    for (int i1 = 0; i1 < 30; ++i1) {
        __syncthreads();   // P0 strip + P1[i1-1] visible

        if (w < 4) {
            // ---------- conv1 row i1: waves 0-3, nt=w, 2 passes of 2 mtiles ----------
            int rbase = (i1 % 6) * 30;
            int xr = ch >> 3;
            #pragma unroll
            for (int half = 0; half < 2; ++half) {
                #pragma unroll
                for (int i = 0; i < 4; ++i) acc[i] = (f32x4){0.f,0.f,0.f,0.f};
                #pragma unroll
                for (int pr = 0; pr < 4; ++pr) {
                    int sbase = ((2*i1 + pr) & 3) * 264;
                    #pragma unroll
                    for (int v = 0; v < 3; ++v) {
                        #pragma unroll
                        for (int mtl = 0; mtl < 2; ++mtl) {
                            int col = (2*half + mtl)*16 + l15 + v;
                            int unit = sbase + (col>>1)*8 + ((4*(col&1) + lc) ^ ((col>>1)&7));
                            short8 a = *(const short8*)(smem + OFF_P0 + unit*16);
                            if (pr <= 2)
                                acc[mtl*2+0] = __builtin_amdgcn_mfma_f32_16x16x32_bf16(
                                    a, wf[pr*3+v], acc[mtl*2+0], 0, 0, 0);
                            if (pr >= 1)
                                acc[mtl*2+1] = __builtin_amdgcn_mfma_f32_16x16x32_bf16(
                                    a, wf[(pr-1)*3+v], acc[mtl*2+1], 0, 0, 0);
                        }
                    }
                }
                // epilogue: premax -> +bias -> GELU -> P1 ring row i1%6
                #pragma unroll
                for (int mtl = 0; mtl < 2; ++mtl) {
                    int pcol = (2*half + mtl)*8 + lc*2;
                    if (pcol < 30) {
                        f32x4 A0 = acc[mtl*2+0], A1 = acc[mtl*2+1];
                        float p0 = fmaxf(fmaxf(A0[0], A0[1]), fmaxf(A1[0], A1[1]));
                        float p1 = fmaxf(fmaxf(A0[2], A0[3]), fmaxf(A1[2], A1[3]));
                        float m0 = gelu_f(p0 + bias);
                        float m1 = gelu_f(p1 + bias);
                        int u0 = (rbase + pcol)*8     + (xr ^ (pcol & 7));
                        int u1 = (rbase + pcol + 1)*8 + (xr ^ ((pcol+1) & 7));
                        *(unsigned short*)(smem + OFF_P1 + u0*16 + (ch&7)*2) = f2bf(m0);
                        *(unsigned short*)(smem + OFF_P1 + u1*16 + (ch&7)*2) = f2bf(m1);
                    }
                }
            }
        } else if (i1 >= 4 && (i1 & 1) == 0) {
            // ---------- conv2 row i2: waves 4-7, nt=w-4, 2 mtiles ----------
            const int i2 = (i1 - 4) >> 1;
            #pragma unroll
            for (int i = 0; i < 4; ++i) acc[i] = (f32x4){0.f,0.f,0.f,0.f};
            #pragma unroll
            for (int pr = 0; pr < 4; ++pr) {
                int rb = ((2*i2 + pr) % 6) * 30;
                #pragma unroll
                for (int v = 0; v < 3; ++v) {
                    #pragma unroll
                    for (int mt = 0; mt < 2; ++mt) {
                        int col = mt*16 + l15 + v;
                        #pragma unroll
                        for (int kh = 0; kh < 2; ++kh) {
                            int unit = (rb + col)*8 + ((kh*4 + lc) ^ (col & 7));
                            short8 a = *(const short8*)(smem + OFF_P1 + unit*16);
                            if (pr <= 2)
                                acc[mt*2+0] = __builtin_amdgcn_mfma_f32_16x16x32_bf16(
                                    a, wf[kh*9 + pr*3+v], acc[mt*2+0], 0, 0, 0);
                            if (pr >= 1)
                                acc[mt*2+1] = __builtin_amdgcn_mfma_f32_16x16x32_bf16(
                                    a, wf[kh*9 + (pr-1)*3+v], acc[mt*2+1], 0, 0, 0);
                        }
                    }
                }
            }
            // epilogue: exact GELU x8 then max -> out
            #pragma unroll
            for (int mt = 0; mt < 2; ++mt) {
                int pcol = mt*8 + lc*2;
                if (pcol < 14) {
                    f32x4 A0 = acc[mt*2+0], A1 = acc[mt*2+1];
                    float g00 = gelu_f(A0[0] + bias), g01 = gelu_f(A0[1] + bias);
                    float g02 = gelu_f(A0[2] + bias), g03 = gelu_f(A0[3] + bias);
                    float g10 = gelu_f(A1[0] + bias), g11 = gelu_f(A1[1] + bias);
                    float g12 = gelu_f(A1[2] + bias), g13 = gelu_f(A1[3] + bias);
                    float m0 = fmaxf(fmaxf(g00, g01), fmaxf(g10, g11));
                    float m1 = fmaxf(fmaxf(g02, g03), fmaxf(g12, g13));
                    float2 st; st.x = m0; st.y = m1;
                    *(float2*)(out + obase + ch*196 + i2*14 + pcol) = st;
                }
            }
        }

        __syncthreads();   // conv1 reads of P0 done; P1 row i1 done
        if (i1 < 29) produce(smem, tys, b0r, c0w, tid, 2*i1 + 4);
    }

    __syncthreads();
    // tail: conv2 row 13 (P1 rows 26..29)
    if (w >= 4) {
        const int i2 = 13;
        #pragma unroll
        for (int i = 0; i < 4; ++i) acc[i] = (f32x4){0.f,0.f,0.f,0.f};
        #pragma unroll
        for (int pr = 0; pr < 4; ++pr) {
            int rb = ((2*i2 + pr) % 6) * 30;
            #pragma unroll
            for (int v = 0; v < 3; ++v) {
                #pragma unroll
                for (int mt = 0; mt < 2; ++mt) {
                    int col = mt*16 + l15 + v;
                    #pragma unroll
                    for (int kh = 0; kh < 2; ++kh) {
                        int unit = (rb + col)*8 + ((kh*4 + lc) ^ (col & 7));
                        short8 a = *(const short8*)(smem + OFF_P1 + unit*16);
                        if (pr <= 2)
                            acc[mt*2+0] = __builtin_amdgcn_mfma_f32_16x16x32_bf16(
                                a, wf[kh*9 + pr*3+v], acc[mt*2+0], 0, 0, 0);
                        if (pr >= 1)
                            acc[mt*2+1] = __builtin_amdgcn_mfma_f32_16x16x32_bf16(
                                a, wf[kh*9 + (pr-1)*3+v], acc[mt*2+1], 0, 0, 0);
                    }
                }
            }
        }
        #pragma unroll
        for (int mt = 0; mt < 2; ++mt) {
            int pcol = mt*8 + lc*2;
            if (pcol < 14) {
                f32x4 A0 = acc[mt*2+0], A1 = acc[mt*2+1];
                float g00 = gelu_f(A0[0] + bias), g01 = gelu_f(A0[1] + bias);
                float g02 = gelu_f(A0[2] + bias), g03 = gelu_f(A0[3] + bias);
                float g10 = gelu_f(A1[0] + bias), g11 = gelu_f(A1[1] + bias);
                float g12 = gelu_f(A1[2] + bias), g13 = gelu_f(A1[3] + bias);
                float m0 = fmaxf(fmaxf(g00, g01), fmaxf(g10, g11));
                float m1 = fmaxf(fmaxf(g02, g03), fmaxf(g12, g13));
                float2 st; st.x = m0; st.y = m1;
                *(float2*)(out + obase + ch*196 + i2*14 + pcol) = st;
            }
        }
    }
}

extern "C" void kernel_launch(void* const* d_in, const int* in_sizes, int n_in,
                              void* d_out, int out_size, void* d_ws, size_t ws_size,
                              hipStream_t stream) {
    const float* token = (const float*)d_in[0];
    const float* type_ = (const float*)d_in[1];
    const float* w0 = (const float*)d_in[2];
    const float* b0 = (const float*)d_in[3];
    const float* w1 = (const float*)d_in[4];
    const float* b1 = (const float*)d_in[5];
    const float* w2 = (const float*)d_in[6];
    const float* b2 = (const float*)d_in[7];
    float* out = (float*)d_out;

    hipLaunchKernelGGL(conv_pipeline, dim3(512), dim3(512), LDS_TOTAL, stream,
                       token, type_, w0, b0, w1, b1, w2, b2, out);
}

// Round 11
// 192.561 us; speedup vs baseline: 1.1728x; 1.1728x over previous
//
#include <hip/hip_runtime.h>

// Conv2dFusion v7: single-barrier pipeline with MFMA/VALU interleave, 1 block/CU.
// Per image: 128x128 rank-1 map -> conv0(1->32)+GELU+pool (VALU, H-table, GELU-after-max)
//   -> conv1(32->64)+GELU+pool (MFMA, waves 0-3) -> P1 6-row LDS ring
//   -> conv2(64->64)+GELU+pool (MFMA, waves 4-7) -> out.
// v7 (round-10 lessons):
//   - REVERT all register forcing: (512,4) and waves_per_eu(4) both cap at 64
//     VGPR and spill ~150 MB/dispatch. v5 config (112 VGPR, no spill) restored.
//   - P0 ring 4 -> 6 slots: produce(2i1+4,5) writes slots disjoint (mod 6) from
//     conv1(i1) reads {2i1..2i1+3} -> produce merges into the compute phase.
//     ONE __syncthreads() per iteration instead of two.
//   - produce split into 8 chunks, interleaved between conv1's 8 (half,pr)
//     MFMA sub-blocks / conv2's 4 pr-blocks, so issue order alternates
//     MFMA clusters and conv0 VALU -> both pipes fed from the same wave.

typedef short short8 __attribute__((ext_vector_type(8)));
typedef float f32x4 __attribute__((ext_vector_type(4)));

#define OFF_TY   0                    // f32[128] = 512 B
#define OFF_HLO  512                  // u32[32*126] = 16128 B
#define OFF_HHI  16640                // u16[32*126] = 8064 B
#define OFF_P0   24704                // 6 slots * 264 units * 16B = 25344 B
#define OFF_P1   50048                // 1472 units * 16B = 23552 B
#define OFF_TK   OFF_P1               // f32[128] staging, dead before P1 writes
#define LDS_TOTAL (50048 + 23552)     // 73,600 B

__device__ __forceinline__ unsigned short f2bf(float f) {
    unsigned int u = __float_as_uint(f);
    u += 0x7fffu + ((u >> 16) & 1u);   // RNE
    return (unsigned short)(u >> 16);
}

// erf-GELU via A&S 7.1.25 (|err| <= 2.5e-5), branch-free.
__device__ __forceinline__ float gelu_f(float x) {
    float ax = __builtin_fabsf(x);
    float E  = __builtin_amdgcn_exp2f(x * x * -0.72134752f);
    float k  = __builtin_amdgcn_rcpf(__builtin_fmaf(0.33267686f, ax, 1.0f));
    float s  = __builtin_fmaf(0.7478556f, k, -0.0958798f);
    s = __builtin_fmaf(s, k, 0.3480242f);
    s = s * k;
    float erfabs = __builtin_fmaf(-s, E, 1.0f);
    return __builtin_fmaf(0.5f * ax, erfabs, 0.5f * x);
}

// One chunk (k) of the pool0 producer: one pooled output per thread.
// rest = (tid>>5) + 16*k ; rows R0(+1) of pooled stage-0 into P0 ring (%6 slots).
__device__ __forceinline__ void produce_chunk(char* smem,
                                              float t0, float t1, float t2,
                                              float t3, float t4, float t5,
                                              float b0r, int c, int rest, int R0) {
    if (rest < 126) {   // k<=6: compiler folds to true (rest<=111)
        int roff = (rest >= 63) ? 1 : 0;
        int q = rest - (roff ? 63 : 0);
        float s0 = roff ? t2 : t0;
        float s1 = roff ? t3 : t1;
        float s2 = roff ? t4 : t2;
        float s3 = roff ? t5 : t3;
        uint2 lo = *(const uint2*)(smem + OFF_HLO + (c*126 + 2*q)*4);
        unsigned int hi = *(const unsigned int*)(smem + OFF_HHI + (c*126 + 2*q)*2);
        float h00 = __uint_as_float(lo.x << 16);
        float h10 = __uint_as_float(lo.x & 0xffff0000u);
        float h01 = __uint_as_float(lo.y << 16);
        float h11 = __uint_as_float(lo.y & 0xffff0000u);
        float h20 = __uint_as_float(hi << 16);
        float h21 = __uint_as_float(hi & 0xffff0000u);
        float e00 = __builtin_fmaf(s0,h00, __builtin_fmaf(s1,h10, __builtin_fmaf(s2,h20, b0r)));
        float e10 = __builtin_fmaf(s1,h00, __builtin_fmaf(s2,h10, __builtin_fmaf(s3,h20, b0r)));
        float e01 = __builtin_fmaf(s0,h01, __builtin_fmaf(s1,h11, __builtin_fmaf(s2,h21, b0r)));
        float e11 = __builtin_fmaf(s1,h01, __builtin_fmaf(s2,h11, __builtin_fmaf(s3,h21, b0r)));
        float m = gelu_f(fmaxf(fmaxf(e00, e01), fmaxf(e10, e11)));
        int slot = (R0 + roff) % 6;
        int unit = slot*264 + (q>>1)*8 + ((4*(q&1) + (c>>3)) ^ ((q>>1)&7));
        *(unsigned short*)(smem + OFF_P0 + unit*16 + (c&7)*2) = f2bf(m);
    }
}

__launch_bounds__(512, 2)
__global__ void conv_pipeline(const float* __restrict__ token,
                              const float* __restrict__ type_,
                              const float* __restrict__ w0, const float* __restrict__ b0,
                              const float* __restrict__ w1, const float* __restrict__ b1,
                              const float* __restrict__ w2, const float* __restrict__ b2,
                              float* __restrict__ out) {
    extern __shared__ char smem[];
    float* tys = (float*)(smem + OFF_TY);
    float* tks = (float*)(smem + OFF_TK);

    const int tid = threadIdx.x;
    const int img = blockIdx.x;
    const int w   = tid >> 6;
    const int l   = tid & 63;
    const int l15 = l & 15;
    const int lc  = l >> 4;
    const int c0w = tid & 31;
    const int rest0 = tid >> 5;

    for (int i = tid; i < 128; i += 512) {
        tys[i] = type_[img*128 + i];
        tks[i] = token[img*128 + i];
    }

    const float b0r = b0[c0w];

    __syncthreads();   // ty/tk visible

    // H[c][x][u] = sum_v w0[c,u,v]*tk[x+v]  (w0r lives only in this scope)
    {
        float w0r[9];
        #pragma unroll
        for (int i = 0; i < 9; ++i) w0r[i] = w0[c0w*9 + i];
        int x = tid >> 5;
        #pragma unroll
        for (int k = 0; k < 8; ++k, x += 16) {
            if (x < 126) {
                float t0 = tks[x], t1 = tks[x+1], t2 = tks[x+2];
                float h0 = __builtin_fmaf(w0r[0],t0, __builtin_fmaf(w0r[1],t1, w0r[2]*t2));
                float h1 = __builtin_fmaf(w0r[3],t0, __builtin_fmaf(w0r[4],t1, w0r[5]*t2));
                float h2 = __builtin_fmaf(w0r[6],t0, __builtin_fmaf(w0r[7],t1, w0r[8]*t2));
                unsigned int lov = (unsigned int)f2bf(h0) | ((unsigned int)f2bf(h1) << 16);
                *(unsigned int*)(smem + OFF_HLO + (c0w*126 + x)*4) = lov;
                *(unsigned short*)(smem + OFF_HHI + (c0w*126 + x)*2) = f2bf(h2);
            }
        }
    }

    // Shared fragment storage: waves 0-3 use wf[0..8] (conv1, nt=w),
    // waves 4-7 use wf[0..17] (conv2, nt=w-4, kh*9+uv).
    short8 wf[18];
    float bias;
    const int ch = ((w & 3) * 16) + l15;       // c1 (waves<4) or c2 (waves>=4)
    if (w < 4) {
        bias = b1[ch];
        #pragma unroll
        for (int uv = 0; uv < 9; ++uv) {
            short8 f;
            #pragma unroll
            for (int j = 0; j < 8; ++j)
                f[j] = (short)f2bf(w1[(ch*32 + 8*lc + j)*9 + uv]);
            wf[uv] = f;
        }
    } else {
        bias = b2[ch];
        #pragma unroll
        for (int kh = 0; kh < 2; ++kh)
            #pragma unroll
            for (int uv = 0; uv < 9; ++uv) {
                short8 f;
                #pragma unroll
                for (int j = 0; j < 8; ++j)
                    f[j] = (short)f2bf(w2[(ch*64 + kh*32 + 8*lc + j)*9 + uv]);
                wf[kh*9 + uv] = f;
            }
    }

    __syncthreads();   // H visible (also guards tk death before P1 writes)

    // Prologue: pooled rows 0..3 into P0 slots 0..3.
    {
        float t0 = tys[0], t1 = tys[1], t2 = tys[2],
              t3 = tys[3], t4 = tys[4], t5 = tys[5];
        #pragma unroll
        for (int k = 0; k < 8; ++k)
            produce_chunk(smem, t0,t1,t2,t3,t4,t5, b0r, c0w, rest0 + 16*k, 0);
        t0 = tys[4]; t1 = tys[5]; t2 = tys[6];
        t3 = tys[7]; t4 = tys[8]; t5 = tys[9];
        #pragma unroll
        for (int k = 0; k < 8; ++k)
            produce_chunk(smem, t0,t1,t2,t3,t4,t5, b0r, c0w, rest0 + 16*k, 2);
    }
    __syncthreads();

    const size_t obase = (size_t)img * 12544;

    for (int i1 = 0; i1 < 30; ++i1) {
        // produce rows 2i1+4, 2i1+5 concurrently with conv compute (disjoint %6 slots)
        const int doP = (i1 < 29);
        const int R0p = 2*i1 + 4;
        float t0, t1, t2, t3, t4, t5;
        if (doP) {
            t0 = tys[2*R0p+0]; t1 = tys[2*R0p+1]; t2 = tys[2*R0p+2];
            t3 = tys[2*R0p+3]; t4 = tys[2*R0p+4]; t5 = tys[2*R0p+5];
        }

        if (w < 4) {
            // ---------- conv1 row i1 (waves 0-3, nt=w), produce interleaved ----------
            int rbase = (i1 % 6) * 30;
            int xr = ch >> 3;
            #pragma unroll
            for (int half = 0; half < 2; ++half) {
                f32x4 acc[4];
                #pragma unroll
                for (int i = 0; i < 4; ++i) acc[i] = (f32x4){0.f,0.f,0.f,0.f};
                #pragma unroll
                for (int pr = 0; pr < 4; ++pr) {
                    int sbase = ((2*i1 + pr) % 6) * 264;
                    #pragma unroll
                    for (int v = 0; v < 3; ++v) {
                        #pragma unroll
                        for (int mtl = 0; mtl < 2; ++mtl) {
                            int col = (2*half + mtl)*16 + l15 + v;
                            int unit = sbase + (col>>1)*8 + ((4*(col&1) + lc) ^ ((col>>1)&7));
                            short8 a = *(const short8*)(smem + OFF_P0 + unit*16);
                            if (pr <= 2)
                                acc[mtl*2+0] = __builtin_amdgcn_mfma_f32_16x16x32_bf16(
                                    a, wf[pr*3+v], acc[mtl*2+0], 0, 0, 0);
                            if (pr >= 1)
                                acc[mtl*2+1] = __builtin_amdgcn_mfma_f32_16x16x32_bf16(
                                    a, wf[(pr-1)*3+v], acc[mtl*2+1], 0, 0, 0);
                        }
                    }
                    if (doP) produce_chunk(smem, t0,t1,t2,t3,t4,t5, b0r, c0w,
                                           rest0 + 16*(half*4 + pr), R0p);
                }
                // epilogue: premax -> +bias -> GELU -> P1 ring row i1%6
                #pragma unroll
                for (int mtl = 0; mtl < 2; ++mtl) {
                    int pcol = (2*half + mtl)*8 + lc*2;
                    if (pcol < 30) {
                        f32x4 A0 = acc[mtl*2+0], A1 = acc[mtl*2+1];
                        float p0 = fmaxf(fmaxf(A0[0], A0[1]), fmaxf(A1[0], A1[1]));
                        float p1 = fmaxf(fmaxf(A0[2], A0[3]), fmaxf(A1[2], A1[3]));
                        float m0 = gelu_f(p0 + bias);
                        float m1 = gelu_f(p1 + bias);
                        int u0 = (rbase + pcol)*8     + (xr ^ (pcol & 7));
                        int u1 = (rbase + pcol + 1)*8 + (xr ^ ((pcol+1) & 7));
                        *(unsigned short*)(smem + OFF_P1 + u0*16 + (ch&7)*2) = f2bf(m0);
                        *(unsigned short*)(smem + OFF_P1 + u1*16 + (ch&7)*2) = f2bf(m1);
                    }
                }
            }
        } else if (i1 >= 4 && (i1 & 1) == 0) {
            // ---------- conv2 row i2 (waves 4-7, nt=w-4), produce interleaved ----------
            const int i2 = (i1 - 4) >> 1;
            f32x4 acc[4];
            #pragma unroll
            for (int i = 0; i < 4; ++i) acc[i] = (f32x4){0.f,0.f,0.f,0.f};
            #pragma unroll
            for (int pr = 0; pr < 4; ++pr) {
                int rb = ((2*i2 + pr) % 6) * 30;
                #pragma unroll
                for (int v = 0; v < 3; ++v) {
                    #pragma unroll
                    for (int mt = 0; mt < 2; ++mt) {
                        int col = mt*16 + l15 + v;
                        #pragma unroll
                        for (int kh = 0; kh < 2; ++kh) {
                            int unit = (rb + col)*8 + ((kh*4 + lc) ^ (col & 7));
                            short8 a = *(const short8*)(smem + OFF_P1 + unit*16);
                            if (pr <= 2)
                                acc[mt*2+0] = __builtin_amdgcn_mfma_f32_16x16x32_bf16(
                                    a, wf[kh*9 + pr*3+v], acc[mt*2+0], 0, 0, 0);
                            if (pr >= 1)
                                acc[mt*2+1] = __builtin_amdgcn_mfma_f32_16x16x32_bf16(
                                    a, wf[kh*9 + (pr-1)*3+v], acc[mt*2+1], 0, 0, 0);
                        }
                    }
                }
                if (doP) {
                    produce_chunk(smem, t0,t1,t2,t3,t4,t5, b0r, c0w, rest0 + 16*(2*pr),   R0p);
                    produce_chunk(smem, t0,t1,t2,t3,t4,t5, b0r, c0w, rest0 + 16*(2*pr+1), R0p);
                }
            }
            // epilogue: exact GELU x8 then max -> out
            #pragma unroll
            for (int mt = 0; mt < 2; ++mt) {
                int pcol = mt*8 + lc*2;
                if (pcol < 14) {
                    f32x4 A0 = acc[mt*2+0], A1 = acc[mt*2+1];
                    float g00 = gelu_f(A0[0] + bias), g01 = gelu_f(A0[1] + bias);
                    float g02 = gelu_f(A0[2] + bias), g03 = gelu_f(A0[3] + bias);
                    float g10 = gelu_f(A1[0] + bias), g11 = gelu_f(A1[1] + bias);
                    float g12 = gelu_f(A1[2] + bias), g13 = gelu_f(A1[3] + bias);
                    float m0 = fmaxf(fmaxf(g00, g01), fmaxf(g10, g11));
                    float m1 = fmaxf(fmaxf(g02, g03), fmaxf(g12, g13));
                    float2 st; st.x = m0; st.y = m1;
                    *(float2*)(out + obase + ch*196 + i2*14 + pcol) = st;
                }
            }
        } else {
            // conv2 waves, odd iteration: produce only
            if (doP) {
                #pragma unroll
                for (int k = 0; k < 8; ++k)
                    produce_chunk(smem, t0,t1,t2,t3,t4,t5, b0r, c0w, rest0 + 16*k, R0p);
            }
        }

        __syncthreads();   // P0 rows 2i1+4,5 + P1 row i1 visible next iteration
    }

    // tail: conv2 row 13 (P1 rows 26..29)
    if (w >= 4) {
        const int i2 = 13;
        f32x4 acc[4];
        #pragma unroll
        for (int i = 0; i < 4; ++i) acc[i] = (f32x4){0.f,0.f,0.f,0.f};
        #pragma unroll
        for (int pr = 0; pr < 4; ++pr) {
            int rb = ((2*i2 + pr) % 6) * 30;
            #pragma unroll
            for (int v = 0; v < 3; ++v) {
                #pragma unroll
                for (int mt = 0; mt < 2; ++mt) {
                    int col = mt*16 + l15 + v;
                    #pragma unroll
                    for (int kh = 0; kh < 2; ++kh) {
                        int unit = (rb + col)*8 + ((kh*4 + lc) ^ (col & 7));
                        short8 a = *(const short8*)(smem + OFF_P1 + unit*16);
                        if (pr <= 2)
                            acc[mt*2+0] = __builtin_amdgcn_mfma_f32_16x16x32_bf16(
                                a, wf[kh*9 + pr*3+v], acc[mt*2+0], 0, 0, 0);
                        if (pr >= 1)
                            acc[mt*2+1] = __builtin_amdgcn_mfma_f32_16x16x32_bf16(
                                a, wf[kh*9 + (pr-1)*3+v], acc[mt*2+1], 0, 0, 0);
                    }
                }
            }
        }
        #pragma unroll
        for (int mt = 0; mt < 2; ++mt) {
            int pcol = mt*8 + lc*2;
            if (pcol < 14) {
                f32x4 A0 = acc[mt*2+0], A1 = acc[mt*2+1];
                float g00 = gelu_f(A0[0] + bias), g01 = gelu_f(A0[1] + bias);
                float g02 = gelu_f(A0[2] + bias), g03 = gelu_f(A0[3] + bias);
                float g10 = gelu_f(A1[0] + bias), g11 = gelu_f(A1[1] + bias);
                float g12 = gelu_f(A1[2] + bias), g13 = gelu_f(A1[3] + bias);
                float m0 = fmaxf(fmaxf(g00, g01), fmaxf(g10, g11));
                float m1 = fmaxf(fmaxf(g02, g03), fmaxf(g12, g13));
                float2 st; st.x = m0; st.y = m1;
                *(float2*)(out + obase + ch*196 + i2*14 + pcol) = st;
            }
        }
    }
}

extern "C" void kernel_launch(void* const* d_in, const int* in_sizes, int n_in,
                              void* d_out, int out_size, void* d_ws, size_t ws_size,
                              hipStream_t stream) {
    const float* token = (const float*)d_in[0];
    const float* type_ = (const float*)d_in[1];
    const float* w0 = (const float*)d_in[2];
    const float* b0 = (const float*)d_in[3];
    const float* w1 = (const float*)d_in[4];
    const float* b1 = (const float*)d_in[5];
    const float* w2 = (const float*)d_in[6];
    const float* b2 = (const float*)d_in[7];
    float* out = (float*)d_out;

    hipLaunchKernelGGL(conv_pipeline, dim3(512), dim3(512), LDS_TOTAL, stream,
                       token, type_, w0, b0, w1, b1, w2, b2, out);
}

// Round 12
// 187.336 us; speedup vs baseline: 1.2055x; 1.0279x over previous
//
#include <hip/hip_runtime.h>

// Conv2dFusion v8: conv0 moved onto the MFMA pipe (f16), VALU-diet build.
// Per image: 128x128 rank-1 map
//   -> conv0(1->32) via MFMA f16 K=3 implicit GEMM, GELU-after-max pool (bursts of
//      16 conv-rows = 8 pooled rows into a 16-slot P0 ring, every 4th iteration)
//   -> conv1(32->64)+GELU+pool (MFMA bf16, waves 0-3) -> P1 6-row LDS ring
//   -> conv2(64->64)+GELU+pool (MFMA bf16, waves 4-7, even iters) -> out.
// Round-11 evidence: kernel is VALU-instruction-bound (53% VALUBusy == inst census;
// produce() was 54% of VALU inst; MfmaUtil only 18%). conv0-as-MFMA removes the
// 12 FMA + 6 unpack per pooled output; pool window lands in-lane (C rows = y,
// x even/odd = 2 MFMAs in the same lane) so no cross-lane ops are added.
// Numerics: H bf16->f16 (better), ty f32->f16 (2^-11); downstream unchanged.
// Register lessons kept: no waves_per_eu forcing (spills at 64-VGPR cap);
// __launch_bounds__(512,2); wf[18] stays in regs (~110 VGPR, 1 block/CU).

typedef short short8 __attribute__((ext_vector_type(8)));
typedef _Float16 half8 __attribute__((ext_vector_type(8)));
typedef float f32x4 __attribute__((ext_vector_type(4)));
typedef unsigned int uint4v __attribute__((ext_vector_type(4)));

#define OFF_TY   0                     // f32[132] = 528 B (rounded to 544)
#define OFF_H16  544                   // (126*32) * 8 B (f16 h0,h1,h2,pad) = 32256
#define OFF_P0   32800                 // 16 slots * 264 units * 16 B = 67584
#define OFF_P1   100384                // 1472 units * 16 B = 23552
#define OFF_TK   OFF_P0                // f32[128] staging, dead before first P0 write
#define LDS_TOTAL 123936               // <= 128 KiB dynamic LDS (verified OK on gfx950)

__device__ __forceinline__ unsigned short f2bf(float f) {
    unsigned int u = __float_as_uint(f);
    u += 0x7fffu + ((u >> 16) & 1u);   // RNE
    return (unsigned short)(u >> 16);
}

__device__ __forceinline__ unsigned int pack2h(float a, float b) {
    union { _Float16 h[2]; unsigned int u; } p;
    p.h[0] = (_Float16)a;              // v_cvt_f16_f32, RNE
    p.h[1] = (_Float16)b;
    return p.u;
}

// erf-GELU via A&S 7.1.25 (|err| <= 2.5e-5), branch-free.
__device__ __forceinline__ float gelu_f(float x) {
    float ax = __builtin_fabsf(x);
    float E  = __builtin_amdgcn_exp2f(x * x * -0.72134752f);
    float k  = __builtin_amdgcn_rcpf(__builtin_fmaf(0.33267686f, ax, 1.0f));
    float s  = __builtin_fmaf(0.7478556f, k, -0.0958798f);
    s = __builtin_fmaf(s, k, 0.3480242f);
    s = s * k;
    float erfabs = __builtin_fmaf(-s, E, 1.0f);
    return __builtin_fmaf(0.5f * ax, erfabs, 0.5f * x);
}

// conv0 burst: pooled rows pbase..pbase+7 (conv rows 2*pbase..2*pbase+15) via
// MFMA f16. A[m=y][k=u] = ty[y_base+m+u] (k>=3 killed by B zeros); B[k=u][n=c] =
// H[c][x][u]. Per unit (x-pair q, ctile): 2 MFMA -> per lane 2 pooled outputs
// (c = ct*16+l15 fixed, Y = pbase+2*lc, pbase+2*lc+1). Units split 12/20 between
// conv1/conv2 waves for barrier balance.
__device__ __forceinline__ void conv0_burst(char* smem, const float* tys,
                                            int w, int l15, int lc,
                                            float b00, float b01, int pbase) {
    const int y_base = 2 * pbase;
    half8 afrag;
    {
        float a0 = tys[y_base + l15 + 0];
        float a1 = tys[y_base + l15 + 1];
        float a2 = tys[y_base + l15 + 2];
        float a3 = tys[y_base + l15 + 3];
        union { uint4v u; half8 h; } av;
        av.u = (uint4v){ pack2h(a0, a1), pack2h(a2, a3), 0u, 0u };
        afrag = av.h;   // lanes lc!=0 hold k=8..: B is zero there, product is 0
    }
    const f32x4 ci0 = (f32x4){b00, b00, b00, b00};
    const f32x4 ci1 = (f32x4){b01, b01, b01, b01};
    const int base = (w < 4) ? w * 12 : 48 + (w - 4) * 20;
    const int cnt  = (w < 4) ? 12 : ((w == 7) ? 18 : 20);

    #pragma unroll
    for (int j = 0; j < 20; ++j) {
        if (j < cnt) {
            const int uid = base + j;          // 0..125 = (x-pair 0..62) x (ctile 0..1)
            const int q  = uid >> 1;
            const int ct = uid & 1;
            const char* hp = smem + OFF_H16 + ((2*q)*32 + ct*16 + l15) * 8;
            uint2 hA = *(const uint2*)(hp);
            uint2 hB = *(const uint2*)(hp + 256);   // x+1 row (32*8 B)
            if (lc != 0) { hA.x = 0u; hA.y = 0u; hB.x = 0u; hB.y = 0u; }
            union { uint4v u; half8 h; } ba, bb;
            ba.u = (uint4v){hA.x, hA.y, 0u, 0u};
            bb.u = (uint4v){hB.x, hB.y, 0u, 0u};
            const f32x4 ci = ct ? ci1 : ci0;
            f32x4 cA = __builtin_amdgcn_mfma_f32_16x16x32_f16(afrag, ba.h, ci, 0, 0, 0);
            f32x4 cB = __builtin_amdgcn_mfma_f32_16x16x32_f16(afrag, bb.h, ci, 0, 0, 0);
            float m0 = gelu_f(fmaxf(fmaxf(cA[0], cA[1]), fmaxf(cB[0], cB[1])));
            float m1 = gelu_f(fmaxf(fmaxf(cA[2], cA[3]), fmaxf(cB[2], cB[3])));
            const int c = ct * 16 + l15;
            const int upos = (q >> 1) * 8 + ((4 * (q & 1) + (c >> 3)) ^ ((q >> 1) & 7));
            const int p0 = pbase + 2 * lc;
            const int s0 = p0 & 15, s1 = (p0 + 1) & 15;
            *(unsigned short*)(smem + OFF_P0 + (s0 * 264 + upos) * 16 + (c & 7) * 2) = f2bf(m0);
            *(unsigned short*)(smem + OFF_P0 + (s1 * 264 + upos) * 16 + (c & 7) * 2) = f2bf(m1);
        }
    }
}

__launch_bounds__(512, 2)
__global__ void conv_pipeline(const float* __restrict__ token,
                              const float* __restrict__ type_,
                              const float* __restrict__ w0, const float* __restrict__ b0,
                              const float* __restrict__ w1, const float* __restrict__ b1,
                              const float* __restrict__ w2, const float* __restrict__ b2,
                              float* __restrict__ out) {
    extern __shared__ char smem[];
    float* tys = (float*)(smem + OFF_TY);
    float* tks = (float*)(smem + OFF_TK);

    const int tid = threadIdx.x;
    const int img = blockIdx.x;
    const int w   = tid >> 6;
    const int l   = tid & 63;
    const int l15 = l & 15;
    const int lc  = l >> 4;
    const int c0w = tid & 31;

    for (int i = tid; i < 132; i += 512) {
        tys[i] = (i < 128) ? type_[img*128 + i] : 0.f;   // pad: burst rows 62/63 read ty[128..130]
        if (i < 128) tks[i] = token[img*128 + i];
    }

    const float b00 = b0[l15];
    const float b01 = b0[l15 + 16];

    __syncthreads();   // ty/tk visible

    // H16[x][c] = (h0,h1,h2,0) f16, h_u = sum_v w0[c,u,v]*tk[x+v]
    {
        float w0r[9];
        #pragma unroll
        for (int i = 0; i < 9; ++i) w0r[i] = w0[c0w*9 + i];
        int x = tid >> 5;
        #pragma unroll
        for (int k = 0; k < 8; ++k, x += 16) {
            if (x < 126) {
                float t0 = tks[x], t1 = tks[x+1], t2 = tks[x+2];
                float h0 = __builtin_fmaf(w0r[0],t0, __builtin_fmaf(w0r[1],t1, w0r[2]*t2));
                float h1 = __builtin_fmaf(w0r[3],t0, __builtin_fmaf(w0r[4],t1, w0r[5]*t2));
                float h2 = __builtin_fmaf(w0r[6],t0, __builtin_fmaf(w0r[7],t1, w0r[8]*t2));
                uint2 hv; hv.x = pack2h(h0, h1); hv.y = pack2h(h2, 0.f);
                *(uint2*)(smem + OFF_H16 + (x*32 + c0w)*8) = hv;
            }
        }
    }

    // Shared fragment storage: waves 0-3 use wf[0..8] (conv1, nt=w),
    // waves 4-7 use wf[0..17] (conv2, nt=w-4, kh*9+uv).
    short8 wf[18];
    float bias;
    const int ch = ((w & 3) * 16) + l15;
    if (w < 4) {
        bias = b1[ch];
        #pragma unroll
        for (int uv = 0; uv < 9; ++uv) {
            short8 f;
            #pragma unroll
            for (int j = 0; j < 8; ++j)
                f[j] = (short)f2bf(w1[(ch*32 + 8*lc + j)*9 + uv]);
            wf[uv] = f;
        }
    } else {
        bias = b2[ch];
        #pragma unroll
        for (int kh = 0; kh < 2; ++kh)
            #pragma unroll
            for (int uv = 0; uv < 9; ++uv) {
                short8 f;
                #pragma unroll
                for (int j = 0; j < 8; ++j)
                    f[j] = (short)f2bf(w2[(ch*64 + kh*32 + 8*lc + j)*9 + uv]);
                wf[kh*9 + uv] = f;
            }
    }

    __syncthreads();   // H16 visible; tks dead (aliases P0)

    conv0_burst(smem, tys, w, l15, lc, b00, b01, 0);   // pooled rows 0..7
    __syncthreads();

    const size_t obase = (size_t)img * 12544;

    for (int i1 = 0; i1 < 30; ++i1) {
        if (w < 4) {
            // ---------- conv1 row i1 (waves 0-3, nt=w), 2 passes of 2 mtiles ----------
            int rbase = (i1 % 6) * 30;
            int xr = ch >> 3;
            #pragma unroll
            for (int half = 0; half < 2; ++half) {
                f32x4 acc[4];
                #pragma unroll
                for (int i = 0; i < 4; ++i) acc[i] = (f32x4){0.f,0.f,0.f,0.f};
                #pragma unroll
                for (int pr = 0; pr < 4; ++pr) {
                    int sbase = ((2*i1 + pr) & 15) * 264;
                    #pragma unroll
                    for (int v = 0; v < 3; ++v) {
                        #pragma unroll
                        for (int mtl = 0; mtl < 2; ++mtl) {
                            int col = (2*half + mtl)*16 + l15 + v;
                            int unit = sbase + (col>>1)*8 + ((4*(col&1) + lc) ^ ((col>>1)&7));
                            short8 a = *(const short8*)(smem + OFF_P0 + unit*16);
                            if (pr <= 2)
                                acc[mtl*2+0] = __builtin_amdgcn_mfma_f32_16x16x32_bf16(
                                    a, wf[pr*3+v], acc[mtl*2+0], 0, 0, 0);
                            if (pr >= 1)
                                acc[mtl*2+1] = __builtin_amdgcn_mfma_f32_16x16x32_bf16(
                                    a, wf[(pr-1)*3+v], acc[mtl*2+1], 0, 0, 0);
                        }
                    }
                }
                #pragma unroll
                for (int mtl = 0; mtl < 2; ++mtl) {
                    int pcol = (2*half + mtl)*8 + lc*2;
                    if (pcol < 30) {
                        f32x4 A0 = acc[mtl*2+0], A1 = acc[mtl*2+1];
                        float p0 = fmaxf(fmaxf(A0[0], A0[1]), fmaxf(A1[0], A1[1]));
                        float p1 = fmaxf(fmaxf(A0[2], A0[3]), fmaxf(A1[2], A1[3]));
                        float m0 = gelu_f(p0 + bias);
                        float m1 = gelu_f(p1 + bias);
                        int u0 = (rbase + pcol)*8     + (xr ^ (pcol & 7));
                        int u1 = (rbase + pcol + 1)*8 + (xr ^ ((pcol+1) & 7));
                        *(unsigned short*)(smem + OFF_P1 + u0*16 + (ch&7)*2) = f2bf(m0);
                        *(unsigned short*)(smem + OFF_P1 + u1*16 + (ch&7)*2) = f2bf(m1);
                    }
                }
            }
        } else if (i1 >= 4 && (i1 & 1) == 0) {
            // ---------- conv2 row i2 (waves 4-7, nt=w-4), 2 mtiles ----------
            const int i2 = (i1 - 4) >> 1;
            f32x4 acc[4];
            #pragma unroll
            for (int i = 0; i < 4; ++i) acc[i] = (f32x4){0.f,0.f,0.f,0.f};
            #pragma unroll
            for (int pr = 0; pr < 4; ++pr) {
                int rb = ((2*i2 + pr) % 6) * 30;
                #pragma unroll
                for (int v = 0; v < 3; ++v) {
                    #pragma unroll
                    for (int mt = 0; mt < 2; ++mt) {
                        int col = mt*16 + l15 + v;
                        #pragma unroll
                        for (int kh = 0; kh < 2; ++kh) {
                            int unit = (rb + col)*8 + ((kh*4 + lc) ^ (col & 7));
                            short8 a = *(const short8*)(smem + OFF_P1 + unit*16);
                            if (pr <= 2)
                                acc[mt*2+0] = __builtin_amdgcn_mfma_f32_16x16x32_bf16(
                                    a, wf[kh*9 + pr*3+v], acc[mt*2+0], 0, 0, 0);
                            if (pr >= 1)
                                acc[mt*2+1] = __builtin_amdgcn_mfma_f32_16x16x32_bf16(
                                    a, wf[kh*9 + (pr-1)*3+v], acc[mt*2+1], 0, 0, 0);
                        }
                    }
                }
            }
            #pragma unroll
            for (int mt = 0; mt < 2; ++mt) {
                int pcol = mt*8 + lc*2;
                if (pcol < 14) {
                    f32x4 A0 = acc[mt*2+0], A1 = acc[mt*2+1];
                    float g00 = gelu_f(A0[0] + bias), g01 = gelu_f(A0[1] + bias);
                    float g02 = gelu_f(A0[2] + bias), g03 = gelu_f(A0[3] + bias);
                    float g10 = gelu_f(A1[0] + bias), g11 = gelu_f(A1[1] + bias);
                    float g12 = gelu_f(A1[2] + bias), g13 = gelu_f(A1[3] + bias);
                    float m0 = fmaxf(fmaxf(g00, g01), fmaxf(g10, g11));
                    float m1 = fmaxf(fmaxf(g02, g03), fmaxf(g12, g13));
                    float2 st; st.x = m0; st.y = m1;
                    *(float2*)(out + obase + ch*196 + i2*14 + pcol) = st;
                }
            }
        }

        // conv0 burst every 4th iter: pooled rows 2i1+4..2i1+11 (slots (2i1+4..11)&15,
        // disjoint from this iteration's conv1 read slots (2i1..2i1+3)&15).
        if ((i1 & 3) == 2) conv0_burst(smem, tys, w, l15, lc, b00, b01, 2*i1 + 4);

        __syncthreads();
    }

    // tail: conv2 row 13 (P1 rows 26..29)
    if (w >= 4) {
        const int i2 = 13;
        f32x4 acc[4];
        #pragma unroll
        for (int i = 0; i < 4; ++i) acc[i] = (f32x4){0.f,0.f,0.f,0.f};
        #pragma unroll
        for (int pr = 0; pr < 4; ++pr) {
            int rb = ((2*i2 + pr) % 6) * 30;
            #pragma unroll
            for (int v = 0; v < 3; ++v) {
                #pragma unroll
                for (int mt = 0; mt < 2; ++mt) {
                    int col = mt*16 + l15 + v;
                    #pragma unroll
                    for (int kh = 0; kh < 2; ++kh) {
                        int unit = (rb + col)*8 + ((kh*4 + lc) ^ (col & 7));
                        short8 a = *(const short8*)(smem + OFF_P1 + unit*16);
                        if (pr <= 2)
                            acc[mt*2+0] = __builtin_amdgcn_mfma_f32_16x16x32_bf16(
                                a, wf[kh*9 + pr*3+v], acc[mt*2+0], 0, 0, 0);
                        if (pr >= 1)
                            acc[mt*2+1] = __builtin_amdgcn_mfma_f32_16x16x32_bf16(
                                a, wf[kh*9 + (pr-1)*3+v], acc[mt*2+1], 0, 0, 0);
                    }
                }
            }
        }
        #pragma unroll
        for (int mt = 0; mt < 2; ++mt) {
            int pcol = mt*8 + lc*2;
            if (pcol < 14) {
                f32x4 A0 = acc[mt*2+0], A1 = acc[mt*2+1];
                float g00 = gelu_f(A0[0] + bias), g01 = gelu_f(A0[1] + bias);
                float g02 = gelu_f(A0[2] + bias), g03 = gelu_f(A0[3] + bias);
                float g10 = gelu_f(A1[0] + bias), g11 = gelu_f(A1[1] + bias);
                float g12 = gelu_f(A1[2] + bias), g13 = gelu_f(A1[3] + bias);
                float m0 = fmaxf(fmaxf(g00, g01), fmaxf(g10, g11));
                float m1 = fmaxf(fmaxf(g02, g03), fmaxf(g12, g13));
                float2 st; st.x = m0; st.y = m1;
                *(float2*)(out + obase + ch*196 + i2*14 + pcol) = st;
            }
        }
    }
}

extern "C" void kernel_launch(void* const* d_in, const int* in_sizes, int n_in,
                              void* d_out, int out_size, void* d_ws, size_t ws_size,
                              hipStream_t stream) {
    const float* token = (const float*)d_in[0];
    const float* type_ = (const float*)d_in[1];
    const float* w0 = (const float*)d_in[2];
    const float* b0 = (const float*)d_in[3];
    const float* w1 = (const float*)d_in[4];
    const float* b1 = (const float*)d_in[5];
    const float* w2 = (const float*)d_in[6];
    const float* b2 = (const float*)d_in[7];
    float* out = (float*)d_out;

    hipLaunchKernelGGL(conv_pipeline, dim3(512), dim3(512), LDS_TOTAL, stream,
                       token, type_, w0, b0, w1, b1, w2, b2, out);
}